// Round 1
// baseline (51453.644 us; speedup 1.0000x reference)
//
#include <hip/hip_runtime.h>
#include <math.h>

// Problem constants (fixed by setup_inputs)
#define BSZ   8
#define TSTEPS 10
#define FLEN  10
#define HID   64
#define HW    4096            // 64*64
#define IMG   (HID * HW)      // per-batch h/c plane: 262144 floats
#define OC4   (4 * HID)       // 256 gate output channels

__device__ __forceinline__ float sigmoidf_(float x) {
    return 1.0f / (1.0f + __expf(-x));
}

// Accumulate a 3x3 conv contribution for one input-channel image into a
// 16-pixel row-segment accumulator. img: 64x64 plane. w9: 9 weights (uniform).
__device__ __forceinline__ void conv3x3_acc(const float* __restrict__ img,
                                            const float* __restrict__ w9,
                                            int y, int x0, float acc[16]) {
#pragma unroll
    for (int dy = 0; dy < 3; dy++) {
        int yy = y + dy - 1;
        if (yy < 0 || yy >= 64) continue;
        const float* row = img + yy * 64;
        float r[18];
#pragma unroll
        for (int j = 0; j < 18; j++) {
            int xx = x0 - 1 + j;
            r[j] = (xx >= 0 && xx < 64) ? row[xx] : 0.0f;
        }
#pragma unroll
        for (int px = 0; px < 16; px++) {
#pragma unroll
            for (int dx = 0; dx < 3; dx++) {
                acc[px] = fmaf(w9[dy * 3 + dx], r[px + dx], acc[px]);
            }
        }
    }
}

// pre[b][oc][*] = conv(xin, Wx)[b][oc] + conv(h, Wh)[b][oc]
// grid: (oc=256, b=8), block: 256 threads; thread t -> row y=t/4, cols (t%4)*16 .. +15
__global__ __launch_bounds__(256) void gate_conv(
    const float* __restrict__ xin, int xin_bstride, int icx,
    const float* __restrict__ h,
    const float* __restrict__ Wx, const float* __restrict__ Wh,
    float* __restrict__ pre) {
    const int oc = blockIdx.x;
    const int b  = blockIdx.y;
    const int t  = threadIdx.x;
    const int y  = t >> 2;
    const int x0 = (t & 3) << 4;

    float acc[16];
#pragma unroll
    for (int i = 0; i < 16; i++) acc[i] = 0.0f;

    // x-path
    for (int ic = 0; ic < icx; ic++) {
        const float* wp = Wx + (oc * icx + ic) * 9;   // uniform across block -> scalar loads
        float w9[9];
#pragma unroll
        for (int k = 0; k < 9; k++) w9[k] = wp[k];
        conv3x3_acc(xin + b * xin_bstride + ic * HW, w9, y, x0, acc);
    }
    // h-path (always 64 in-channels)
    for (int ic = 0; ic < HID; ic++) {
        const float* wp = Wh + (oc * HID + ic) * 9;
        float w9[9];
#pragma unroll
        for (int k = 0; k < 9; k++) w9[k] = wp[k];
        conv3x3_acc(h + b * IMG + ic * HW, w9, y, x0, acc);
    }

    float* o = pre + ((size_t)(b * OC4 + oc)) * HW + y * 64 + x0;
#pragma unroll
    for (int i = 0; i < 16; i++) o[i] = acc[i];
}

// Elementwise LSTM cell update. i over B*IMG elements.
// pre layout: (B, 4, HID, H, W); Wc/bias: (4, HID, H, W); h/c: (B, HID, H, W)
__global__ __launch_bounds__(256) void cell_update(
    const float* __restrict__ pre, const float* __restrict__ Wc,
    const float* __restrict__ bias, float* __restrict__ hbuf,
    float* __restrict__ cbuf) {
    int i = blockIdx.x * 256 + threadIdx.x;   // 0 .. B*IMG-1
    int b = i >> 18;                          // / IMG (262144 = 2^18)
    int r = i & (IMG - 1);
    float cv = cbuf[i];
    const float* pb = pre + (size_t)b * (4 * IMG);
    float p0 = pb[r]           + Wc[r]           * cv + bias[r];
    float p1 = pb[IMG + r]     + Wc[IMG + r]     * cv + bias[IMG + r];
    float p2 = pb[2 * IMG + r] + Wc[2 * IMG + r] * cv + bias[2 * IMG + r];
    float p3 = pb[3 * IMG + r] + Wc[3 * IMG + r] * cv + bias[3 * IMG + r];
    float ig = sigmoidf_(p0);
    float fg = sigmoidf_(p1);
    float gg = tanhf(p2);
    float og = sigmoidf_(p3);
    float cn = fg * cv + ig * gg;
    cbuf[i] = cn;
    hbuf[i] = og * tanhf(cn);
}

// out[b][f][0][y][x] = sigmoid(conv(h1, fin_w)[b][0][y][x] + fin_b)
// grid: (16 tiles, b=8), block 256, one pixel per thread
__global__ __launch_bounds__(256) void final_conv(
    const float* __restrict__ h, const float* __restrict__ fw,
    const float* __restrict__ fb, float* __restrict__ out, int f) {
    int b = blockIdx.y;
    int p = blockIdx.x * 256 + threadIdx.x;   // 0..4095
    int y = p >> 6;
    int x = p & 63;
    float acc = fb[0];
    for (int ic = 0; ic < HID; ic++) {
        const float* img = h + (size_t)b * IMG + ic * HW;
        const float* w = fw + ic * 9;          // uniform -> scalar loads
#pragma unroll
        for (int dy = 0; dy < 3; dy++) {
            int yy = y + dy - 1;
            if (yy < 0 || yy >= 64) continue;
#pragma unroll
            for (int dx = 0; dx < 3; dx++) {
                int xx = x + dx - 1;
                if (xx < 0 || xx >= 64) continue;
                acc = fmaf(w[dy * 3 + dx], img[yy * 64 + xx], acc);
            }
        }
    }
    out[((size_t)(b * FLEN + f)) * HW + p] = sigmoidf_(acc);
}

extern "C" void kernel_launch(void* const* d_in, const int* in_sizes, int n_in,
                              void* d_out, int out_size, void* d_ws, size_t ws_size,
                              hipStream_t stream) {
    const float* x = (const float*)d_in[0];
    // d_in[1..16]: {enc0,enc1,dec0,dec1} x {Wx, Wh, Wc, b}
    const float* enc0_Wx = (const float*)d_in[1];
    const float* enc0_Wh = (const float*)d_in[2];
    const float* enc0_Wc = (const float*)d_in[3];
    const float* enc0_b  = (const float*)d_in[4];
    const float* enc1_Wx = (const float*)d_in[5];
    const float* enc1_Wh = (const float*)d_in[6];
    const float* enc1_Wc = (const float*)d_in[7];
    const float* enc1_b  = (const float*)d_in[8];
    const float* dec0_Wx = (const float*)d_in[9];
    const float* dec0_Wh = (const float*)d_in[10];
    const float* dec0_Wc = (const float*)d_in[11];
    const float* dec0_b  = (const float*)d_in[12];
    const float* dec1_Wx = (const float*)d_in[13];
    const float* dec1_Wh = (const float*)d_in[14];
    const float* dec1_Wc = (const float*)d_in[15];
    const float* dec1_b  = (const float*)d_in[16];
    const float* fin_w   = (const float*)d_in[17];
    const float* fin_b   = (const float*)d_in[18];
    float* out = (float*)d_out;

    // Workspace layout (floats): 8 state buffers of B*IMG, then pre (B*4*IMG)
    float* ws  = (float*)d_ws;
    const size_t SB = (size_t)BSZ * IMG;   // 2097152 floats
    float* eh0 = ws + 0 * SB;
    float* ec0 = ws + 1 * SB;
    float* eh1 = ws + 2 * SB;
    float* ec1 = ws + 3 * SB;
    float* dh0 = ws + 4 * SB;
    float* dc0 = ws + 5 * SB;
    float* dh1 = ws + 6 * SB;
    float* dc1 = ws + 7 * SB;
    float* pre = ws + 8 * SB;              // B*4*IMG = 8388608 floats

    // Zero all 8 state buffers (contiguous)
    hipMemsetAsync(ws, 0, 8 * SB * sizeof(float), stream);

    dim3 gconv(OC4, BSZ);
    dim3 gcell((BSZ * IMG) / 256);
    dim3 gfin(16, BSZ);

    // Encoder: T steps, 2 cells each
    for (int t = 0; t < TSTEPS; t++) {
        gate_conv<<<gconv, 256, 0, stream>>>(x + (size_t)t * HW, TSTEPS * HW, 1,
                                             eh0, enc0_Wx, enc0_Wh, pre);
        cell_update<<<gcell, 256, 0, stream>>>(pre, enc0_Wc, enc0_b, eh0, ec0);
        gate_conv<<<gconv, 256, 0, stream>>>(eh0, IMG, HID,
                                             eh1, enc1_Wx, enc1_Wh, pre);
        cell_update<<<gcell, 256, 0, stream>>>(pre, enc1_Wc, enc1_b, eh1, ec1);
    }

    // Decoder: F steps; first input = encoder top hidden, then own h1
    for (int f = 0; f < FLEN; f++) {
        const float* s = (f == 0) ? eh1 : dh1;
        gate_conv<<<gconv, 256, 0, stream>>>(s, IMG, HID,
                                             dh0, dec0_Wx, dec0_Wh, pre);
        cell_update<<<gcell, 256, 0, stream>>>(pre, dec0_Wc, dec0_b, dh0, dc0);
        gate_conv<<<gconv, 256, 0, stream>>>(dh0, IMG, HID,
                                             dh1, dec1_Wx, dec1_Wh, pre);
        cell_update<<<gcell, 256, 0, stream>>>(pre, dec1_Wc, dec1_b, dh1, dc1);
        final_conv<<<gfin, 256, 0, stream>>>(dh1, fin_w, fin_b, out, f);
    }
}

// Round 2
// 2287.348 us; speedup vs baseline: 22.4949x; 22.4949x over previous
//
#include <hip/hip_runtime.h>
#include <hip/hip_bf16.h>
#include <math.h>

// Problem constants (fixed by setup_inputs)
#define BSZ    8
#define TSTEPS 10
#define FLEN   10
#define HID    64
#define HW     4096                 // 64*64
#define IMG    (HID * HW)           // 262144
#define OC4    (4 * HID)            // 256 gate channels
#define KTOT   1152                 // 2 paths * 9 taps * 64 ch
#define PADW   66
#define PADIMG (PADW * PADW * HID)  // one batch padded NHWC plane: 278784 elems
#define PADSZ  (BSZ * PADIMG)       // 2230272 bf16 elems
#define SB     (BSZ * IMG)          // 2097152 floats (one h/c state)

typedef __attribute__((ext_vector_type(8))) short bf16x8;
typedef __attribute__((ext_vector_type(4))) float f32x4;

__device__ __forceinline__ float sigmoidf_(float x) {
    return 1.0f / (1.0f + __expf(-x));
}

// ---------------------------------------------------------------------------
// Weight reorder: Wx(256,icx,3,3) + Wh(256,64,3,3) fp32 -> Bw[oc=256][k=1152]
// bf16, k = path*576 + tap*64 + ic  (tap = ky*3+kx). ic >= icx in path0 -> 0.
__global__ __launch_bounds__(256) void reorder_w(
    const float* __restrict__ Wx, int icx,
    const float* __restrict__ Wh, __hip_bfloat16* __restrict__ Bw) {
    int oc = blockIdx.x;
    for (int k = threadIdx.x; k < KTOT; k += 256) {
        int path = k >= 576;
        int rem = k - path * 576;
        int tap = rem >> 6;
        int ic = rem & 63;
        float v;
        if (!path) v = (ic < icx) ? Wx[(oc * icx + ic) * 9 + tap] : 0.0f;
        else       v = Wh[(oc * HID + ic) * 9 + tap];
        Bw[oc * KTOT + k] = __float2bfloat16(v);
    }
}

// ---------------------------------------------------------------------------
// Pack x_t (B,1,64,64 fp32) into padded NHWC bf16 buffer, channel 0 only.
// Channels 1..63 and the border stay zero from the launch-start memset.
__global__ __launch_bounds__(256) void pack_x(
    const float* __restrict__ x, int t, __hip_bfloat16* __restrict__ px) {
    int i = blockIdx.x * 256 + threadIdx.x;   // 0..32767
    int b = i >> 12, p = i & 4095, y = p >> 6, xx = p & 63;
    px[((b * PADW + y + 1) * PADW + (xx + 1)) * HID] =
        __float2bfloat16(x[(b * TSTEPS + t) * HW + p]);
}

// ---------------------------------------------------------------------------
// im2col GEMM: C[oc][px] = sum_k Bw[oc][k] * im2col(src0,src1)[px][k]
// M = 256 (oc), N = 32768 (b*4096+p), K = 1152 (18 chunks of 64).
// Block 256 thr = 4 waves, 128x128 tile; wave (wr,wc) does 64x64 via 4x4
// 16x16x32 bf16 MFMAs. A (weights) in As, B (pixels) in Bs, both row-major
// [row][64] bf16 staged with global_load_lds width 16 (linear layout).
__global__ __launch_bounds__(256) void gemm_cell(
    const __hip_bfloat16* __restrict__ Bw,
    const __hip_bfloat16* __restrict__ src0,
    const __hip_bfloat16* __restrict__ src1,
    float* __restrict__ pre) {
    __shared__ short As[128 * 64];
    __shared__ short Bs[128 * 64];
    const int tid  = threadIdx.x;
    const int lane = tid & 63;
    const int wave = tid >> 6;
    const int quad = lane >> 4;
    const int l15  = lane & 15;
    const int wr = wave >> 1;            // oc 64-half
    const int wc = wave & 1;             // px 64-half
    const int px0 = blockIdx.x * 128;
    const int oc0 = blockIdx.y * 128;

    // Per-staging-iteration source bases (element units), K-invariant.
    int a_off[4], s_off[4];
#pragma unroll
    for (int it = 0; it < 4; it++) {
        int idx = it * 256 + tid;
        int rr = idx >> 3, seg = idx & 7;
        a_off[it] = (oc0 + rr) * KTOT + seg * 8;
        int px = px0 + rr;
        int b = px >> 12, p = px & 4095, y = p >> 6, x = p & 63;
        s_off[it] = ((b * PADW + y + 1) * PADW + (x + 1)) * HID + seg * 8;
    }
    const int ldsbase = (tid & ~63) * 8;   // wave-uniform lane0 elem offset

    f32x4 acc[4][4] = {};

    for (int kk = 0; kk < 18; kk++) {
        const __hip_bfloat16* src = (kk < 9) ? src0 : src1;
        int tap = (kk < 9) ? kk : kk - 9;
        int dd = ((tap / 3) - 1) * (PADW * HID) + ((tap % 3) - 1) * HID;
        int ka = kk * 64;
#pragma unroll
        for (int it = 0; it < 4; it++) {
            __builtin_amdgcn_global_load_lds(
                (const __attribute__((address_space(1))) void*)(Bw + a_off[it] + ka),
                (__attribute__((address_space(3))) void*)(&As[it * 2048 + ldsbase]),
                16, 0, 0);
            __builtin_amdgcn_global_load_lds(
                (const __attribute__((address_space(1))) void*)(src + s_off[it] + dd),
                (__attribute__((address_space(3))) void*)(&Bs[it * 2048 + ldsbase]),
                16, 0, 0);
        }
        __syncthreads();
#pragma unroll
        for (int k2 = 0; k2 < 2; k2++) {
            bf16x8 af[4], bfr[4];
#pragma unroll
            for (int i = 0; i < 4; i++)
                af[i] = *(const bf16x8*)&As[(wr * 64 + i * 16 + l15) * 64 + k2 * 32 + quad * 8];
#pragma unroll
            for (int j = 0; j < 4; j++)
                bfr[j] = *(const bf16x8*)&Bs[(wc * 64 + j * 16 + l15) * 64 + k2 * 32 + quad * 8];
#pragma unroll
            for (int i = 0; i < 4; i++)
#pragma unroll
                for (int j = 0; j < 4; j++)
                    acc[i][j] = __builtin_amdgcn_mfma_f32_16x16x32_bf16(
                        af[i], bfr[j], acc[i][j], 0, 0, 0);
        }
        __syncthreads();
    }

    // Epilogue: C row = oc (quad*4+reg), col = px (lane&15) -> coalesced.
#pragma unroll
    for (int i = 0; i < 4; i++) {
        int oc = oc0 + wr * 64 + i * 16 + quad * 4;
#pragma unroll
        for (int j = 0; j < 4; j++) {
            int px = px0 + wc * 64 + j * 16 + l15;
            int b = px >> 12, p = px & 4095;
#pragma unroll
            for (int r = 0; r < 4; r++) {
                pre[((size_t)(b * OC4 + oc + r)) * HW + p] = acc[i][j][r];
            }
        }
    }
}

// ---------------------------------------------------------------------------
// LSTM cell elementwise update + bf16 NHWC re-pack of h into padded buffer.
// pre: (B,4,HID,H,W) fp32; Wc/bias: (4,HID,H,W); cbuf: (B,HID,H,W).
__global__ __launch_bounds__(256) void cell_update_pack(
    const float* __restrict__ pre, const float* __restrict__ Wc,
    const float* __restrict__ bias, float* __restrict__ cbuf,
    __hip_bfloat16* __restrict__ hpack) {
    int i = blockIdx.x * 256 + threadIdx.x;   // 0 .. B*IMG-1
    int b = i >> 18;
    int r = i & (IMG - 1);
    float cv = cbuf[i];
    const float* pb = pre + (size_t)b * (4 * IMG);
    float p0 = pb[r]           + Wc[r]           * cv + bias[r];
    float p1 = pb[IMG + r]     + Wc[IMG + r]     * cv + bias[IMG + r];
    float p2 = pb[2 * IMG + r] + Wc[2 * IMG + r] * cv + bias[2 * IMG + r];
    float p3 = pb[3 * IMG + r] + Wc[3 * IMG + r] * cv + bias[3 * IMG + r];
    float ig = sigmoidf_(p0);
    float fg = sigmoidf_(p1);
    float gg = tanhf(p2);
    float og = sigmoidf_(p3);
    float cn = fg * cv + ig * gg;
    cbuf[i] = cn;
    float hn = og * tanhf(cn);
    int hid = r >> 12, p = r & 4095, y = p >> 6, x = p & 63;
    hpack[((b * PADW + y + 1) * PADW + (x + 1)) * HID + hid] = __float2bfloat16(hn);
}

// ---------------------------------------------------------------------------
// Final 1-out-channel 3x3 conv + sigmoid, reading the packed bf16 h (padded,
// NHWC -> no boundary checks). grid (16,B), one pixel per thread.
__global__ __launch_bounds__(256) void final_conv(
    const __hip_bfloat16* __restrict__ ph, const float* __restrict__ fw,
    const float* __restrict__ fb, float* __restrict__ out, int f) {
    int b = blockIdx.y;
    int p = blockIdx.x * 256 + threadIdx.x;
    int y = p >> 6, x = p & 63;
    float acc = fb[0];
#pragma unroll
    for (int tap = 0; tap < 9; tap++) {
        const __hip_bfloat16* base =
            ph + ((b * PADW + y + (tap / 3)) * PADW + (x + (tap % 3))) * HID;
        for (int ic = 0; ic < HID; ic++)
            acc = fmaf(__bfloat162float(base[ic]), fw[ic * 9 + tap], acc);
    }
    out[((size_t)(b * FLEN + f)) * HW + p] = sigmoidf_(acc);
}

// ---------------------------------------------------------------------------
extern "C" void kernel_launch(void* const* d_in, const int* in_sizes, int n_in,
                              void* d_out, int out_size, void* d_ws, size_t ws_size,
                              hipStream_t stream) {
    const float* x = (const float*)d_in[0];
    const float* Wx_[4] = {(const float*)d_in[1], (const float*)d_in[5],
                           (const float*)d_in[9], (const float*)d_in[13]};
    const float* Wh_[4] = {(const float*)d_in[2], (const float*)d_in[6],
                           (const float*)d_in[10], (const float*)d_in[14]};
    const float* Wc_[4] = {(const float*)d_in[3], (const float*)d_in[7],
                           (const float*)d_in[11], (const float*)d_in[15]};
    const float* b_[4]  = {(const float*)d_in[4], (const float*)d_in[8],
                           (const float*)d_in[12], (const float*)d_in[16]};
    const float* fin_w  = (const float*)d_in[17];
    const float* fin_b  = (const float*)d_in[18];
    float* out = (float*)d_out;

    // Workspace: [c0..c3 fp32][5 padded bf16][pre fp32][Bw bf16 x4]
    char* wsb = (char*)d_ws;
    const size_t CB_BYTES  = (size_t)4 * SB * sizeof(float);        // 33,554,432
    const size_t PAD_BYTES = (size_t)5 * PADSZ * sizeof(short);     // 22,302,720
    const size_t ZERO_BYTES = CB_BYTES + PAD_BYTES;                 // 55,857,152
    const size_t PRE_BYTES = (size_t)BSZ * OC4 * HW * sizeof(float);// 33,554,432

    float* cbuf = (float*)wsb;                         // 4 states
    __hip_bfloat16* pads = (__hip_bfloat16*)(wsb + CB_BYTES);
    float* pre = (float*)(wsb + ZERO_BYTES);
    __hip_bfloat16* bw = (__hip_bfloat16*)(wsb + ZERO_BYTES + PRE_BYTES);

    float* ec0 = cbuf + 0 * SB;
    float* ec1 = cbuf + 1 * SB;
    float* dc0 = cbuf + 2 * SB;
    float* dc1 = cbuf + 3 * SB;
    __hip_bfloat16* px  = pads + 0 * PADSZ;   // packed x_t (ch0 live)
    __hip_bfloat16* pe0 = pads + 1 * PADSZ;   // packed enc0 h
    __hip_bfloat16* pe1 = pads + 2 * PADSZ;   // packed enc1 h
    __hip_bfloat16* pd0 = pads + 3 * PADSZ;   // packed dec0 h
    __hip_bfloat16* pd1 = pads + 4 * PADSZ;   // packed dec1 h
    __hip_bfloat16* bw_e0 = bw + 0 * (OC4 * KTOT);
    __hip_bfloat16* bw_e1 = bw + 1 * (OC4 * KTOT);
    __hip_bfloat16* bw_d0 = bw + 2 * (OC4 * KTOT);
    __hip_bfloat16* bw_d1 = bw + 3 * (OC4 * KTOT);

    // Zero c-states + all padded buffers (borders / spare channels).
    hipMemsetAsync(wsb, 0, ZERO_BYTES, stream);

    // Reorder weights (per call; inputs restored before every timed launch).
    reorder_w<<<dim3(OC4), 256, 0, stream>>>(Wx_[0], 1,   Wh_[0], bw_e0);
    reorder_w<<<dim3(OC4), 256, 0, stream>>>(Wx_[1], HID, Wh_[1], bw_e1);
    reorder_w<<<dim3(OC4), 256, 0, stream>>>(Wx_[2], HID, Wh_[2], bw_d0);
    reorder_w<<<dim3(OC4), 256, 0, stream>>>(Wx_[3], HID, Wh_[3], bw_d1);

    dim3 ggemm(256, 2);                       // N=32768/128, M=256/128
    dim3 gcell((BSZ * IMG) / 256);
    dim3 gfin(16, BSZ);
    dim3 gpack((BSZ * HW) / 256);

    // Encoder
    for (int t = 0; t < TSTEPS; t++) {
        pack_x<<<gpack, 256, 0, stream>>>(x, t, px);
        gemm_cell<<<ggemm, 256, 0, stream>>>(bw_e0, px, pe0, pre);
        cell_update_pack<<<gcell, 256, 0, stream>>>(pre, Wc_[0], b_[0], ec0, pe0);
        gemm_cell<<<ggemm, 256, 0, stream>>>(bw_e1, pe0, pe1, pre);
        cell_update_pack<<<gcell, 256, 0, stream>>>(pre, Wc_[1], b_[1], ec1, pe1);
    }
    // Decoder
    for (int f = 0; f < FLEN; f++) {
        const __hip_bfloat16* s = (f == 0) ? pe1 : pd1;
        gemm_cell<<<ggemm, 256, 0, stream>>>(bw_d0, s, pd0, pre);
        cell_update_pack<<<gcell, 256, 0, stream>>>(pre, Wc_[2], b_[2], dc0, pd0);
        gemm_cell<<<ggemm, 256, 0, stream>>>(bw_d1, pd0, pd1, pre);
        cell_update_pack<<<gcell, 256, 0, stream>>>(pre, Wc_[3], b_[3], dc1, pd1);
        final_conv<<<gfin, 256, 0, stream>>>(pd1, fin_w, fin_b, out, f);
    }
}

// Round 3
// 1568.706 us; speedup vs baseline: 32.8000x; 1.4581x over previous
//
#include <hip/hip_runtime.h>
#include <hip/hip_bf16.h>
#include <math.h>

// Problem constants (fixed by setup_inputs)
#define BSZ    8
#define TSTEPS 10
#define FLEN   10
#define HID    64
#define HW     4096                 // 64*64
#define IMG    (HID * HW)           // 262144
#define OC4    (4 * HID)            // 256 gate channels
#define PADW   66
#define PADIMG (PADW * PADW * HID)  // padded NHWC plane per batch
#define PADSZ  (BSZ * PADIMG)       // 2230272 bf16 elems per buffer
#define SB     (BSZ * IMG)          // 2097152 floats (one c state)
#define KT_E0  640                  // enc0: 1 x-im2col chunk + 9 h chunks
#define KT_STD 1152                 // 9 x chunks + 9 h chunks

typedef __attribute__((ext_vector_type(8))) short bf16x8;
typedef __attribute__((ext_vector_type(4))) float f32x4;

__device__ __forceinline__ float sigmoidf_(float x) {
    return 1.0f / (1.0f + __expf(-x));
}
__device__ __forceinline__ float tanh_fast(float x) {
    float e = __expf(2.0f * x);
    return 1.0f - 2.0f / (e + 1.0f);     // exact at +-inf saturation
}
__device__ __forceinline__ float bf2f(short u) {
    union { unsigned u; float f; } cv;
    cv.u = ((unsigned)(unsigned short)u) << 16;
    return cv.f;
}

// ---------------------------------------------------------------------------
// Weight reorder -> Bw[oc'=hid*4+gate][k], bf16. Source oc = gate*64+hid.
// icx==1 (enc0): chunk0 = x-im2col taps (9 live of 64), chunks 1..9 = Wh taps.
// else: chunks 0..8 = Wx taps, 9..17 = Wh taps (64 ch each).
__global__ __launch_bounds__(256) void reorder_w(
    const float* __restrict__ Wx, int icx,
    const float* __restrict__ Wh, __hip_bfloat16* __restrict__ Bw, int ktot) {
    int ocp = blockIdx.x, hid = ocp >> 2, gate = ocp & 3;
    int oc = gate * 64 + hid;
    for (int k = threadIdx.x; k < ktot; k += 256) {
        int c = k >> 6, j = k & 63;
        float v;
        if (icx == 1) {
            if (c == 0) v = (j < 9) ? Wx[oc * 9 + j] : 0.0f;
            else        v = Wh[(oc * 64 + j) * 9 + (c - 1)];
        } else {
            if (c < 9)  v = Wx[(oc * 64 + j) * 9 + c];
            else        v = Wh[(oc * 64 + j) * 9 + (c - 9)];
        }
        Bw[ocp * ktot + k] = __float2bfloat16(v);
    }
}

// ---------------------------------------------------------------------------
// im2col of x for ALL timesteps: px_all[t][b][y+1][x+1][ch=tap] = x neighbor.
// Channels 9..63 and borders stay zero from the launch-start memset.
__global__ __launch_bounds__(256) void pack_x_all(
    const float* __restrict__ x, __hip_bfloat16* __restrict__ px_all) {
    int i = blockIdx.x * 256 + threadIdx.x;   // 0 .. 10*32768-1
    int t = i >> 15, rem = i & 32767;
    int b = rem >> 12, p = rem & 4095, y = p >> 6, xx = p & 63;
    const float* xb = x + ((size_t)(b * TSTEPS + t)) * HW;
    __hip_bfloat16* o = px_all + (size_t)t * PADSZ +
                        ((b * PADW + y + 1) * PADW + (xx + 1)) * HID;
#pragma unroll
    for (int tap = 0; tap < 9; tap++) {
        int yy = y + tap / 3 - 1, xc = xx + tap % 3 - 1;
        float v = (yy >= 0 && yy < 64 && xc >= 0 && xc < 64) ? xb[yy * 64 + xc] : 0.0f;
        o[tap] = __float2bfloat16(v);
    }
}

// ---------------------------------------------------------------------------
// Fused im2col-GEMM + LSTM cell. M=256 (oc'=hid*4+gate), N=32768 (px), K=ktot.
// 128x128 tile, 4 waves, 4x4 16x16x32 bf16 MFMAs per wave. XOR-swizzled LDS
// (seg ^= row&7) to break the 16-way fragment-read bank conflict while keeping
// the linear lane layout global_load_lds requires. Epilogue: each lane's f32x4
// holds the 4 gates of one (hid,px) -> cell update in-register, write c (fp32)
// and h (bf16, padded NHWC).
template <bool FIRST>
__global__ __launch_bounds__(256) void gemm_cell_fused(
    const __hip_bfloat16* __restrict__ Bw, int ktot, int n0,
    const __hip_bfloat16* __restrict__ src0,
    const __hip_bfloat16* __restrict__ src1,
    const float* __restrict__ Wc, const float* __restrict__ bias,
    float* __restrict__ cbuf, __hip_bfloat16* __restrict__ hout) {
    __shared__ short As[128 * 64];
    __shared__ short Bs[128 * 64];
    const int tid  = threadIdx.x;
    const int lane = tid & 63;
    const int wave = tid >> 6;
    const int quad = lane >> 4;
    const int l15  = lane & 15;
    const int wr = wave >> 1;
    const int wc = wave & 1;
    const int px0 = blockIdx.x * 128;
    const int oc0 = blockIdx.y * 128;

    int a_off[4], s_off[4];
#pragma unroll
    for (int it = 0; it < 4; it++) {
        int idx = it * 256 + tid;
        int rr = idx >> 3, seg = idx & 7;
        int segx = seg ^ (rr & 7);            // global-side swizzle
        a_off[it] = (oc0 + rr) * ktot + segx * 8;
        int px = px0 + rr;
        int b = px >> 12, p = px & 4095, y = p >> 6, x = p & 63;
        s_off[it] = ((b * PADW + y + 1) * PADW + (x + 1)) * HID + segx * 8;
    }
    const int ldsbase = (tid & ~63) * 8;      // wave-uniform
    const int xa = l15 & 7;                   // read-side swizzle (= row&7)

    f32x4 acc[4][4] = {};
    const int nchunks = n0 + 9;

    for (int kk = 0; kk < nchunks; kk++) {
        const __hip_bfloat16* src;
        int tap;
        if (kk < n0) { src = src0; tap = (n0 == 1) ? 4 : kk; }
        else         { src = src1; tap = kk - n0; }
        int dd = ((tap / 3) - 1) * (PADW * HID) + ((tap % 3) - 1) * HID;
        int ka = kk * 64;
#pragma unroll
        for (int it = 0; it < 4; it++) {
            __builtin_amdgcn_global_load_lds(
                (const __attribute__((address_space(1))) void*)(Bw + a_off[it] + ka),
                (__attribute__((address_space(3))) void*)(&As[it * 2048 + ldsbase]),
                16, 0, 0);
            __builtin_amdgcn_global_load_lds(
                (const __attribute__((address_space(1))) void*)(src + s_off[it] + dd),
                (__attribute__((address_space(3))) void*)(&Bs[it * 2048 + ldsbase]),
                16, 0, 0);
        }
        __syncthreads();
#pragma unroll
        for (int k2 = 0; k2 < 2; k2++) {
            int sA = ((k2 * 4 + quad) ^ xa) * 8;
            bf16x8 af[4], bfr[4];
#pragma unroll
            for (int i = 0; i < 4; i++)
                af[i] = *(const bf16x8*)&As[(wr * 64 + i * 16 + l15) * 64 + sA];
#pragma unroll
            for (int j = 0; j < 4; j++)
                bfr[j] = *(const bf16x8*)&Bs[(wc * 64 + j * 16 + l15) * 64 + sA];
#pragma unroll
            for (int i = 0; i < 4; i++)
#pragma unroll
                for (int j = 0; j < 4; j++)
                    acc[i][j] = __builtin_amdgcn_mfma_f32_16x16x32_bf16(
                        af[i], bfr[j], acc[i][j], 0, 0, 0);
        }
        __syncthreads();
    }

    // Epilogue: lane (quad,l15) of wave (wr,wc), tile (i,j):
    //   reg r = gate, hid = oc'/4, px = col -> full cell update in-register.
#pragma unroll
    for (int i = 0; i < 4; i++) {
        int hid = (oc0 >> 2) + wr * 16 + i * 4 + quad;
#pragma unroll
        for (int j = 0; j < 4; j++) {
            int px = px0 + wc * 64 + j * 16 + l15;
            int b = px >> 12, p = px & 4095, y = p >> 6, x = p & 63;
            size_t ci = ((size_t)(b * HID + hid)) * HW + p;
            float cv = FIRST ? 0.0f : cbuf[ci];
            float pg[4];
#pragma unroll
            for (int r = 0; r < 4; r++) {
                int wi = (r * HID + hid) * HW + p;
                float t = acc[i][j][r] + bias[wi];
                if (!FIRST) t += Wc[wi] * cv;
                pg[r] = t;
            }
            float ig = sigmoidf_(pg[0]);
            float fg = sigmoidf_(pg[1]);
            float gg = tanh_fast(pg[2]);
            float og = sigmoidf_(pg[3]);
            float cn = FIRST ? (ig * gg) : (fg * cv + ig * gg);
            cbuf[ci] = cn;
            float hn = og * tanh_fast(cn);
            hout[((b * PADW + y + 1) * PADW + (x + 1)) * HID + hid] =
                __float2bfloat16(hn);
        }
    }
}

// ---------------------------------------------------------------------------
// Final 1-out-channel 3x3 conv + sigmoid over packed bf16 h (padded NHWC).
__global__ __launch_bounds__(256) void final_conv(
    const __hip_bfloat16* __restrict__ ph, const float* __restrict__ fw,
    const float* __restrict__ fb, float* __restrict__ out, int f) {
    int b = blockIdx.y;
    int p = blockIdx.x * 256 + threadIdx.x;
    int y = p >> 6, x = p & 63;
    float acc = fb[0];
#pragma unroll
    for (int tap = 0; tap < 9; tap++) {
        const bf16x8* base = (const bf16x8*)(
            ph + ((b * PADW + y + (tap / 3)) * PADW + (x + (tap % 3))) * HID);
#pragma unroll
        for (int c8 = 0; c8 < 8; c8++) {
            bf16x8 v = base[c8];
#pragma unroll
            for (int jj = 0; jj < 8; jj++)
                acc = fmaf(bf2f(v[jj]), fw[(c8 * 8 + jj) * 9 + tap], acc);
        }
    }
    out[((size_t)(b * FLEN + f)) * HW + p] = sigmoidf_(acc);
}

// ---------------------------------------------------------------------------
extern "C" void kernel_launch(void* const* d_in, const int* in_sizes, int n_in,
                              void* d_out, int out_size, void* d_ws, size_t ws_size,
                              hipStream_t stream) {
    const float* x = (const float*)d_in[0];
    const float* Wx_[4] = {(const float*)d_in[1], (const float*)d_in[5],
                           (const float*)d_in[9], (const float*)d_in[13]};
    const float* Wh_[4] = {(const float*)d_in[2], (const float*)d_in[6],
                           (const float*)d_in[10], (const float*)d_in[14]};
    const float* Wc_[4] = {(const float*)d_in[3], (const float*)d_in[7],
                           (const float*)d_in[11], (const float*)d_in[15]};
    const float* b_[4]  = {(const float*)d_in[4], (const float*)d_in[8],
                           (const float*)d_in[12], (const float*)d_in[16]};
    const float* fin_w  = (const float*)d_in[17];
    const float* fin_b  = (const float*)d_in[18];
    float* out = (float*)d_out;

    // Workspace: [18 padded bf16 buffers][4 c-states fp32][Bw bf16 x4]
    char* wsb = (char*)d_ws;
    const size_t PADS_BYTES = 18ull * PADSZ * sizeof(short);   // 80,289,792
    const size_t C_BYTES    = 4ull * SB * sizeof(float);       // 33,554,432

    __hip_bfloat16* pads = (__hip_bfloat16*)wsb;
    float* cbuf = (float*)(wsb + PADS_BYTES);
    __hip_bfloat16* bw = (__hip_bfloat16*)(wsb + PADS_BYTES + C_BYTES);

    __hip_bfloat16* px_all = pads;                       // 10 buffers
    __hip_bfloat16* e0buf[2] = {pads + 10 * (size_t)PADSZ, pads + 11 * (size_t)PADSZ};
    __hip_bfloat16* e1buf[2] = {pads + 12 * (size_t)PADSZ, pads + 13 * (size_t)PADSZ};
    __hip_bfloat16* d0buf[2] = {pads + 14 * (size_t)PADSZ, pads + 15 * (size_t)PADSZ};
    __hip_bfloat16* d1buf[2] = {pads + 16 * (size_t)PADSZ, pads + 17 * (size_t)PADSZ};

    float* ec0 = cbuf + 0 * (size_t)SB;
    float* ec1 = cbuf + 1 * (size_t)SB;
    float* dc0 = cbuf + 2 * (size_t)SB;
    float* dc1 = cbuf + 3 * (size_t)SB;

    __hip_bfloat16* bw_e0 = bw;
    __hip_bfloat16* bw_e1 = bw_e0 + (size_t)OC4 * KT_E0;
    __hip_bfloat16* bw_d0 = bw_e1 + (size_t)OC4 * KT_STD;
    __hip_bfloat16* bw_d1 = bw_d0 + (size_t)OC4 * KT_STD;

    // Zero all padded bf16 buffers (borders, spare channels, t=0 h-states).
    // c-states need no init: FIRST-step kernels don't read them.
    hipMemsetAsync(wsb, 0, PADS_BYTES, stream);

    reorder_w<<<dim3(OC4), 256, 0, stream>>>(Wx_[0], 1,   Wh_[0], bw_e0, KT_E0);
    reorder_w<<<dim3(OC4), 256, 0, stream>>>(Wx_[1], HID, Wh_[1], bw_e1, KT_STD);
    reorder_w<<<dim3(OC4), 256, 0, stream>>>(Wx_[2], HID, Wh_[2], bw_d0, KT_STD);
    reorder_w<<<dim3(OC4), 256, 0, stream>>>(Wx_[3], HID, Wh_[3], bw_d1, KT_STD);
    pack_x_all<<<dim3((TSTEPS * BSZ * HW) / 256), 256, 0, stream>>>(x, px_all);

    dim3 ggemm(256, 2);      // N=32768/128, M=256/128
    dim3 gfin(16, BSZ);

    // Encoder (double-buffered h: read [pp], write [1-pp])
    int pp = 0;
    for (int t = 0; t < TSTEPS; t++) {
        const __hip_bfloat16* xt = px_all + (size_t)t * PADSZ;
        if (t == 0) {
            gemm_cell_fused<true><<<ggemm, 256, 0, stream>>>(
                bw_e0, KT_E0, 1, xt, e0buf[pp], Wc_[0], b_[0], ec0, e0buf[1 - pp]);
            gemm_cell_fused<true><<<ggemm, 256, 0, stream>>>(
                bw_e1, KT_STD, 9, e0buf[1 - pp], e1buf[pp], Wc_[1], b_[1], ec1, e1buf[1 - pp]);
        } else {
            gemm_cell_fused<false><<<ggemm, 256, 0, stream>>>(
                bw_e0, KT_E0, 1, xt, e0buf[pp], Wc_[0], b_[0], ec0, e0buf[1 - pp]);
            gemm_cell_fused<false><<<ggemm, 256, 0, stream>>>(
                bw_e1, KT_STD, 9, e0buf[1 - pp], e1buf[pp], Wc_[1], b_[1], ec1, e1buf[1 - pp]);
        }
        pp ^= 1;
    }
    // After t=9 (pp was 1), last enc1 write went to e1buf[0].
    __hip_bfloat16* enc_top = e1buf[0];

    // Decoder
    int qq = 0;
    for (int f = 0; f < FLEN; f++) {
        const __hip_bfloat16* s = (f == 0) ? enc_top : d1buf[qq];
        if (f == 0) {
            gemm_cell_fused<true><<<ggemm, 256, 0, stream>>>(
                bw_d0, KT_STD, 9, s, d0buf[qq], Wc_[2], b_[2], dc0, d0buf[1 - qq]);
            gemm_cell_fused<true><<<ggemm, 256, 0, stream>>>(
                bw_d1, KT_STD, 9, d0buf[1 - qq], d1buf[qq], Wc_[3], b_[3], dc1, d1buf[1 - qq]);
        } else {
            gemm_cell_fused<false><<<ggemm, 256, 0, stream>>>(
                bw_d0, KT_STD, 9, s, d0buf[qq], Wc_[2], b_[2], dc0, d0buf[1 - qq]);
            gemm_cell_fused<false><<<ggemm, 256, 0, stream>>>(
                bw_d1, KT_STD, 9, d0buf[1 - qq], d1buf[qq], Wc_[3], b_[3], dc1, d1buf[1 - qq]);
        }
        final_conv<<<gfin, 256, 0, stream>>>(d1buf[1 - qq], fin_w, fin_b, out, f);
        qq ^= 1;
    }
}

// Round 4
// 1566.934 us; speedup vs baseline: 32.8372x; 1.0011x over previous
//
#include <hip/hip_runtime.h>
#include <hip/hip_bf16.h>
#include <math.h>

// Problem constants (fixed by setup_inputs)
#define BSZ    8
#define TSTEPS 10
#define FLEN   10
#define HID    64
#define HW     4096                 // 64*64
#define IMG    (HID * HW)           // 262144
#define OC4    (4 * HID)            // 256 gate channels
#define PADW   66
#define PPIX   (PADW * PADW)        // 4356
#define PADIMG (PPIX * HID)         // padded NHWC plane per batch
#define PADSZ  (BSZ * PADIMG)       // 2230272 bf16 elems per buffer
#define SB     (BSZ * IMG)          // 2097152 floats (one c state)
#define KT_E0  640                  // enc0: 1 x-im2col chunk + 9 h chunks
#define KT_STD 1152                 // 9 x chunks + 9 h chunks

typedef __attribute__((ext_vector_type(8))) short bf16x8;
typedef __attribute__((ext_vector_type(4))) float f32x4;

__device__ __forceinline__ float sigmoidf_(float x) {
    return 1.0f / (1.0f + __expf(-x));
}
__device__ __forceinline__ float tanh_fast(float x) {
    float e = __expf(2.0f * x);
    return 1.0f - 2.0f / (e + 1.0f);     // exact at +-inf saturation
}
__device__ __forceinline__ float bf2f(short u) {
    union { unsigned u; float f; } cv;
    cv.u = ((unsigned)(unsigned short)u) << 16;
    return cv.f;
}
__device__ __forceinline__ short f2bf(float x) {
    __hip_bfloat16 h = __float2bfloat16(x);
    union { __hip_bfloat16 h; short s; } cv; cv.h = h;
    return cv.s;
}

// ---------------------------------------------------------------------------
// Weight reorder -> Bw[oc'=hid*4+gate][k], bf16. Source oc = gate*64+hid.
// icx==1 (enc0): chunk0 = x-im2col taps (9 live of 64), chunks 1..9 = Wh taps.
// else: chunks 0..8 = Wx taps, 9..17 = Wh taps (64 ch each).
__global__ __launch_bounds__(256) void reorder_w(
    const float* __restrict__ Wx, int icx,
    const float* __restrict__ Wh, __hip_bfloat16* __restrict__ Bw, int ktot) {
    int ocp = blockIdx.x, hid = ocp >> 2, gate = ocp & 3;
    int oc = gate * 64 + hid;
    for (int k = threadIdx.x; k < ktot; k += 256) {
        int c = k >> 6, j = k & 63;
        float v;
        if (icx == 1) {
            if (c == 0) v = (j < 9) ? Wx[oc * 9 + j] : 0.0f;
            else        v = Wh[(oc * 64 + j) * 9 + (c - 1)];
        } else {
            if (c < 9)  v = Wx[(oc * 64 + j) * 9 + c];
            else        v = Wh[(oc * 64 + j) * 9 + (c - 9)];
        }
        Bw[ocp * ktot + k] = __float2bfloat16(v);
    }
}

// ---------------------------------------------------------------------------
// Pack Wc + bias -> wcb[hid*HW + p][8] bf16: [Wc g0..g3, bias g0..g3].
__global__ __launch_bounds__(256) void pack_wcb(
    const float* __restrict__ Wc, const float* __restrict__ bias,
    __hip_bfloat16* __restrict__ wcb) {
    int i = blockIdx.x * 256 + threadIdx.x;   // 0 .. HID*HW-1
    int hid = i >> 12, p = i & 4095;
    union { short s[8]; bf16x8 v; } u;
#pragma unroll
    for (int g = 0; g < 4; g++) {
        u.s[g]     = f2bf(Wc[(g * HID + hid) * HW + p]);
        u.s[4 + g] = f2bf(bias[(g * HID + hid) * HW + p]);
    }
    *(bf16x8*)&wcb[(size_t)i * 8] = u.v;
}

// ---------------------------------------------------------------------------
// im2col of x for ALL timesteps into padded NHWC bf16: ch 0..8 = 3x3 taps,
// ch 9..15 zero; ch 16..63 left as poison (only multiplied by zero weights).
// Covers the full 66x66 padded grid (ring written as zeros; never read anyway).
__global__ __launch_bounds__(256) void pack_x_all(
    const float* __restrict__ x, __hip_bfloat16* __restrict__ px_all) {
    int i = blockIdx.x * 256 + threadIdx.x;   // 0 .. 10*8*4356-1
    if (i >= TSTEPS * BSZ * PPIX) return;
    int t = i / (BSZ * PPIX);
    int rem = i - t * (BSZ * PPIX);
    int b = rem / PPIX;
    int pp = rem - b * PPIX;
    int y = pp / PADW, xx = pp - y * PADW;    // padded coords 0..65
    int oy = y - 1, ox = xx - 1;
    const float* xb = x + ((size_t)(b * TSTEPS + t)) * HW;
    bool interior = (oy >= 0 && oy < 64 && ox >= 0 && ox < 64);
    union { short s[16]; bf16x8 v[2]; } u;
#pragma unroll
    for (int tap = 0; tap < 9; tap++) {
        int yy = oy + tap / 3 - 1, xc = ox + tap % 3 - 1;
        float val = (interior && yy >= 0 && yy < 64 && xc >= 0 && xc < 64)
                        ? xb[yy * 64 + xc] : 0.0f;
        u.s[tap] = f2bf(val);
    }
#pragma unroll
    for (int tap = 9; tap < 16; tap++) u.s[tap] = 0;
    short* o = (short*)(px_all + (size_t)t * PADSZ + ((size_t)(b * PPIX + pp)) * HID);
    *(bf16x8*)&o[0] = u.v[0];
    *(bf16x8*)&o[8] = u.v[1];
}

// ---------------------------------------------------------------------------
struct CellArgs {
    const __hip_bfloat16* Bw;
    const __hip_bfloat16* src0;
    const __hip_bfloat16* src1;
    const __hip_bfloat16* wcb;
    float* cbuf;
    __hip_bfloat16* hout;
    int ktot;   // 640 or 1152
    int n0;     // 1 or 9
    int first;  // skip c read (h(-1)=c(-1)=0)
};

// Fused im2col-GEMM + LSTM cell. M=256 (oc'=hid*4+gate), N=32768 (px), K=ktot.
// 128x128 tile, 4 waves, 4x4 16x16x32 bf16 MFMAs per wave, XOR-swizzled LDS.
// blockIdx.z selects one of two independent cell-steps (encoder pipelining).
// Epilogue: in-register cell update; h transposed through LDS -> coalesced
// 16B NHWC stores.
__global__ __launch_bounds__(256) void gemm_cell_fused(CellArgs A0, CellArgs A1) {
    __shared__ short As[128 * 64];
    __shared__ short Bs[128 * 64];
    const bool z1 = (blockIdx.z != 0);
    const __hip_bfloat16* __restrict__ Bw   = z1 ? A1.Bw   : A0.Bw;
    const __hip_bfloat16* __restrict__ src0 = z1 ? A1.src0 : A0.src0;
    const __hip_bfloat16* __restrict__ src1 = z1 ? A1.src1 : A0.src1;
    const __hip_bfloat16* __restrict__ wcb  = z1 ? A1.wcb  : A0.wcb;
    float* __restrict__ cbuf                = z1 ? A1.cbuf : A0.cbuf;
    __hip_bfloat16* __restrict__ hout       = z1 ? A1.hout : A0.hout;
    const int ktot  = z1 ? A1.ktot  : A0.ktot;
    const int n0    = z1 ? A1.n0    : A0.n0;
    const int first = z1 ? A1.first : A0.first;

    const int tid  = threadIdx.x;
    const int lane = tid & 63;
    const int wave = tid >> 6;
    const int quad = lane >> 4;
    const int l15  = lane & 15;
    const int wr = wave >> 1;
    const int wc = wave & 1;
    const int px0 = blockIdx.x * 128;
    const int oc0 = blockIdx.y * 128;

    int a_off[4], s_off[4];
#pragma unroll
    for (int it = 0; it < 4; it++) {
        int idx = it * 256 + tid;
        int rr = idx >> 3, seg = idx & 7;
        int segx = seg ^ (rr & 7);            // global-side swizzle
        a_off[it] = (oc0 + rr) * ktot + segx * 8;
        int px = px0 + rr;
        int b = px >> 12, p = px & 4095, y = p >> 6, x = p & 63;
        s_off[it] = ((b * PADW + y + 1) * PADW + (x + 1)) * HID + segx * 8;
    }
    const int ldsbase = (tid & ~63) * 8;      // wave-uniform
    const int xa = l15 & 7;                   // read-side swizzle (= row&7)

    f32x4 acc[4][4] = {};
    const int nchunks = n0 + 9;

    for (int kk = 0; kk < nchunks; kk++) {
        const __hip_bfloat16* src;
        int tap;
        if (kk < n0) { src = src0; tap = (n0 == 1) ? 4 : kk; }
        else         { src = src1; tap = kk - n0; }
        int dd = ((tap / 3) - 1) * (PADW * HID) + ((tap % 3) - 1) * HID;
        int ka = kk * 64;
#pragma unroll
        for (int it = 0; it < 4; it++) {
            __builtin_amdgcn_global_load_lds(
                (const __attribute__((address_space(1))) void*)(Bw + a_off[it] + ka),
                (__attribute__((address_space(3))) void*)(&As[it * 2048 + ldsbase]),
                16, 0, 0);
            __builtin_amdgcn_global_load_lds(
                (const __attribute__((address_space(1))) void*)(src + s_off[it] + dd),
                (__attribute__((address_space(3))) void*)(&Bs[it * 2048 + ldsbase]),
                16, 0, 0);
        }
        __syncthreads();
#pragma unroll
        for (int k2 = 0; k2 < 2; k2++) {
            int sA = ((k2 * 4 + quad) ^ xa) * 8;
            bf16x8 af[4], bfr[4];
#pragma unroll
            for (int i = 0; i < 4; i++)
                af[i] = *(const bf16x8*)&As[(wr * 64 + i * 16 + l15) * 64 + sA];
#pragma unroll
            for (int j = 0; j < 4; j++)
                bfr[j] = *(const bf16x8*)&Bs[(wc * 64 + j * 16 + l15) * 64 + sA];
#pragma unroll
            for (int i = 0; i < 4; i++)
#pragma unroll
                for (int j = 0; j < 4; j++)
                    acc[i][j] = __builtin_amdgcn_mfma_f32_16x16x32_bf16(
                        af[i], bfr[j], acc[i][j], 0, 0, 0);
        }
        __syncthreads();
    }

    // ---- Epilogue ----------------------------------------------------------
    // Lane (quad,l15) of wave (wr,wc), tile (i,j): reg r = gate,
    // hid = oc'/4, px = col. Cell update in-register; h staged via LDS
    // (stride 40 to break bank conflicts) for coalesced NHWC stores.
    short* hl = As;                       // reuse: all LDS reads fenced above
    const int hid0 = oc0 >> 2;            // 0 or 32
#pragma unroll
    for (int i = 0; i < 4; i++) {
        int hidl = wr * 16 + i * 4 + quad;       // 0..31
        int hid = hid0 + hidl;
#pragma unroll
        for (int j = 0; j < 4; j++) {
            int pxl = wc * 64 + j * 16 + l15;    // 0..127
            int px = px0 + pxl;
            int b = px >> 12, p = px & 4095;
            size_t ci = ((size_t)(b * HID + hid)) * HW + p;
            float cv = first ? 0.0f : cbuf[ci];
            bf16x8 wv = *(const bf16x8*)&wcb[((size_t)hid * HW + p) * 8];
            float pg[4];
#pragma unroll
            for (int r = 0; r < 4; r++)
                pg[r] = acc[i][j][r] + bf2f(wv[r]) * cv + bf2f(wv[4 + r]);
            float ig = sigmoidf_(pg[0]);
            float fg = sigmoidf_(pg[1]);
            float gg = tanh_fast(pg[2]);
            float og = sigmoidf_(pg[3]);
            float cn = fg * cv + ig * gg;
            cbuf[ci] = cn;
            float hn = og * tanh_fast(cn);
            hl[pxl * 40 + hidl] = f2bf(hn);
        }
    }
    __syncthreads();
#pragma unroll
    for (int rnd = 0; rnd < 2; rnd++) {
        int task = rnd * 256 + tid;              // 0..511
        int pxl = task >> 2, q = task & 3;
        bf16x8 v = *(const bf16x8*)&hl[pxl * 40 + q * 8];
        int px = px0 + pxl;
        int b = px >> 12, p = px & 4095, y = p >> 6, x = p & 63;
        *(bf16x8*)&hout[((size_t)((b * PADW + y + 1) * PADW + (x + 1))) * HID
                        + hid0 + q * 8] = v;
    }
}

// ---------------------------------------------------------------------------
// Final 1-out-channel 3x3 conv + sigmoid over packed bf16 h (padded NHWC).
__global__ __launch_bounds__(256) void final_conv(
    const __hip_bfloat16* __restrict__ ph, const float* __restrict__ fw,
    const float* __restrict__ fb, float* __restrict__ out, int f) {
    int b = blockIdx.y;
    int p = blockIdx.x * 256 + threadIdx.x;
    int y = p >> 6, x = p & 63;
    float acc = fb[0];
#pragma unroll
    for (int tap = 0; tap < 9; tap++) {
        const bf16x8* base = (const bf16x8*)(
            ph + ((b * PADW + y + (tap / 3)) * PADW + (x + (tap % 3))) * HID);
#pragma unroll
        for (int c8 = 0; c8 < 8; c8++) {
            bf16x8 v = base[c8];
#pragma unroll
            for (int jj = 0; jj < 8; jj++)
                acc = fmaf(bf2f(v[jj]), fw[(c8 * 8 + jj) * 9 + tap], acc);
        }
    }
    out[((size_t)(b * FLEN + f)) * HW + p] = sigmoidf_(acc);
}

// ---------------------------------------------------------------------------
extern "C" void kernel_launch(void* const* d_in, const int* in_sizes, int n_in,
                              void* d_out, int out_size, void* d_ws, size_t ws_size,
                              hipStream_t stream) {
    const float* x = (const float*)d_in[0];
    const float* Wx_[4] = {(const float*)d_in[1], (const float*)d_in[5],
                           (const float*)d_in[9], (const float*)d_in[13]};
    const float* Wh_[4] = {(const float*)d_in[2], (const float*)d_in[6],
                           (const float*)d_in[10], (const float*)d_in[14]};
    const float* Wc_[4] = {(const float*)d_in[3], (const float*)d_in[7],
                           (const float*)d_in[11], (const float*)d_in[15]};
    const float* b_[4]  = {(const float*)d_in[4], (const float*)d_in[8],
                           (const float*)d_in[12], (const float*)d_in[16]};
    const float* fin_w  = (const float*)d_in[17];
    const float* fin_b  = (const float*)d_in[18];
    float* out = (float*)d_out;

    // Workspace layout:
    //   [8 h double-buffers bf16]  (memset to 0: initial states + halo rings)
    //   [10 px_all bf16]           (written by pack_x_all; poison elsewhere ok)
    //   [4 c states fp32]          (FIRST kernels don't read)
    //   [4 wcb bf16]  [4 Bw bf16]
    char* wsb = (char*)d_ws;
    const size_t H_BYTES  = 8ull * PADSZ * sizeof(short);       // 35,684,352
    const size_t PX_BYTES = 10ull * PADSZ * sizeof(short);      // 44,605,440
    const size_t C_BYTES  = 4ull * SB * sizeof(float);          // 33,554,432
    const size_t WCB_ELEM = (size_t)HID * HW * 8;               // per cell

    __hip_bfloat16* hb = (__hip_bfloat16*)wsb;
    __hip_bfloat16* px_all = (__hip_bfloat16*)(wsb + H_BYTES);
    float* cbuf = (float*)(wsb + H_BYTES + PX_BYTES);
    __hip_bfloat16* wcb = (__hip_bfloat16*)(wsb + H_BYTES + PX_BYTES + C_BYTES);
    __hip_bfloat16* bw = wcb + 4 * WCB_ELEM;

    __hip_bfloat16* e0buf[2] = {hb + 0 * (size_t)PADSZ, hb + 1 * (size_t)PADSZ};
    __hip_bfloat16* e1buf[2] = {hb + 2 * (size_t)PADSZ, hb + 3 * (size_t)PADSZ};
    __hip_bfloat16* d0buf[2] = {hb + 4 * (size_t)PADSZ, hb + 5 * (size_t)PADSZ};
    __hip_bfloat16* d1buf[2] = {hb + 6 * (size_t)PADSZ, hb + 7 * (size_t)PADSZ};

    float* ec0 = cbuf + 0 * (size_t)SB;
    float* ec1 = cbuf + 1 * (size_t)SB;
    float* dc0 = cbuf + 2 * (size_t)SB;
    float* dc1 = cbuf + 3 * (size_t)SB;

    __hip_bfloat16* wcb_[4] = {wcb, wcb + WCB_ELEM, wcb + 2 * WCB_ELEM, wcb + 3 * WCB_ELEM};
    __hip_bfloat16* bw_e0 = bw;
    __hip_bfloat16* bw_e1 = bw_e0 + (size_t)OC4 * KT_E0;
    __hip_bfloat16* bw_d0 = bw_e1 + (size_t)OC4 * KT_STD;
    __hip_bfloat16* bw_d1 = bw_d0 + (size_t)OC4 * KT_STD;
    __hip_bfloat16* bw_[4] = {bw_e0, bw_e1, bw_d0, bw_d1};
    float* c_[4] = {ec0, ec1, dc0, dc1};

    hipMemsetAsync(wsb, 0, H_BYTES, stream);

    reorder_w<<<dim3(OC4), 256, 0, stream>>>(Wx_[0], 1,   Wh_[0], bw_e0, KT_E0);
    reorder_w<<<dim3(OC4), 256, 0, stream>>>(Wx_[1], HID, Wh_[1], bw_e1, KT_STD);
    reorder_w<<<dim3(OC4), 256, 0, stream>>>(Wx_[2], HID, Wh_[2], bw_d0, KT_STD);
    reorder_w<<<dim3(OC4), 256, 0, stream>>>(Wx_[3], HID, Wh_[3], bw_d1, KT_STD);
    for (int cix = 0; cix < 4; cix++)
        pack_wcb<<<dim3((HID * HW) / 256), 256, 0, stream>>>(Wc_[cix], b_[cix], wcb_[cix]);
    pack_x_all<<<dim3((TSTEPS * BSZ * PPIX + 255) / 256), 256, 0, stream>>>(x, px_all);

    auto cellargs = [&](int cell, const __hip_bfloat16* s0, const __hip_bfloat16* s1,
                        __hip_bfloat16* ho, int kt, int nn0, int fi) {
        CellArgs a;
        a.Bw = bw_[cell]; a.src0 = s0; a.src1 = s1; a.wcb = wcb_[cell];
        a.cbuf = c_[cell]; a.hout = ho; a.ktot = kt; a.n0 = nn0; a.first = fi;
        return a;
    };
    auto px = [&](int t) { return px_all + (size_t)t * PADSZ; };

    dim3 gfin(16, BSZ);

    // --- Encoder, software-pipelined: dispatch k runs enc0(t=k) || enc1(t=k-1).
    // e0h(t) lives in e0buf[t&1]; e1h(t) in e1buf[t&1]; t=-1 state = zeros in buf[1].
    {
        CellArgs a = cellargs(0, px(0), e0buf[1], e0buf[0], KT_E0, 1, 1);
        gemm_cell_fused<<<dim3(256, 2, 1), 256, 0, stream>>>(a, a);
    }
    for (int k = 1; k <= 9; k++) {
        int t0 = k, t1 = k - 1;
        CellArgs a0 = cellargs(0, px(t0), e0buf[(t0 - 1) & 1], e0buf[t0 & 1],
                               KT_E0, 1, 0);
        CellArgs a1 = cellargs(1, e0buf[t1 & 1], e1buf[(t1 - 1) & 1], e1buf[t1 & 1],
                               KT_STD, 9, (t1 == 0) ? 1 : 0);
        gemm_cell_fused<<<dim3(256, 2, 2), 256, 0, stream>>>(a0, a1);
    }
    {
        CellArgs a = cellargs(1, e0buf[1], e1buf[0], e1buf[1], KT_STD, 9, 0); // t=9
        gemm_cell_fused<<<dim3(256, 2, 1), 256, 0, stream>>>(a, a);
    }
    __hip_bfloat16* enc_top = e1buf[1];   // e1h(9)

    // --- Decoder (strictly sequential chain)
    for (int f = 0; f < FLEN; f++) {
        const __hip_bfloat16* s = (f == 0) ? enc_top : d1buf[(f - 1) & 1];
        CellArgs a0 = cellargs(2, s, d0buf[(f - 1) & 1], d0buf[f & 1],
                               KT_STD, 9, (f == 0) ? 1 : 0);
        gemm_cell_fused<<<dim3(256, 2, 1), 256, 0, stream>>>(a0, a0);
        CellArgs a1 = cellargs(3, d0buf[f & 1], d1buf[(f - 1) & 1], d1buf[f & 1],
                               KT_STD, 9, (f == 0) ? 1 : 0);
        gemm_cell_fused<<<dim3(256, 2, 1), 256, 0, stream>>>(a1, a1);
        final_conv<<<gfin, 256, 0, stream>>>(d1buf[f & 1], fin_w, fin_b, out, f);
    }
}